// Round 1
// baseline (1197.473 us; speedup 1.0000x reference)
//
#include <hip/hip_runtime.h>

typedef unsigned short ushort_t;
typedef __attribute__((ext_vector_type(8))) short bf16x8;
typedef __attribute__((ext_vector_type(4))) float f32x4;
typedef __attribute__((ext_vector_type(4))) unsigned short u16x4;

#define T_DIM 2048
#define D_DIM 512
#define NH 8
#define NB 2

static __device__ __forceinline__ ushort_t f2bf(float x) {
  union { float f; unsigned u; } v; v.f = x;
  unsigned r = v.u + 0x7fffu + ((v.u >> 16) & 1u);
  return (ushort_t)(r >> 16);
}
static __device__ __forceinline__ float bf2f(ushort_t b) {
  union { unsigned u; float f; } v; v.u = ((unsigned)b) << 16;
  return v.f;
}
static __device__ __forceinline__ f32x4 mfma16(bf16x8 a, bf16x8 b, f32x4 c) {
  return __builtin_amdgcn_mfma_f32_16x16x32_bf16(a, b, c, 0, 0, 0);
}
static __device__ __forceinline__ bf16x8 ld8(const ushort_t* p) {
  return *(const bf16x8*)p;
}

// ---------------- split h -> h_hi/h_lo (bf16) + hT (bf16 transpose) ----------------
__global__ __launch_bounds__(256) void split_h_kernel(const float* __restrict__ h,
    ushort_t* __restrict__ hhi, ushort_t* __restrict__ hlo, ushort_t* __restrict__ hT) {
  __shared__ ushort_t lds[64][68];
  int x = blockIdx.x;                 // 512 = b(2) x tt(32) x ee(8)
  int b = x >> 8, tt = (x >> 3) & 31, ee = x & 7;
  int t0 = tt * 64, e0 = ee * 64;
  int rr = threadIdx.x >> 4;
  int c4 = (threadIdx.x & 15) * 4;
#pragma unroll
  for (int it = 0; it < 4; ++it) {
    int t = it * 16 + rr;
    size_t idx = ((size_t)(b * T_DIM + t0 + t)) * D_DIM + e0 + c4;
    float4 v = *(const float4*)(h + idx);
    u16x4 hv, lv;
    hv[0] = f2bf(v.x); lv[0] = f2bf(v.x - bf2f(hv[0]));
    hv[1] = f2bf(v.y); lv[1] = f2bf(v.y - bf2f(hv[1]));
    hv[2] = f2bf(v.z); lv[2] = f2bf(v.z - bf2f(hv[2]));
    hv[3] = f2bf(v.w); lv[3] = f2bf(v.w - bf2f(hv[3]));
    *(u16x4*)(hhi + idx) = hv;
    *(u16x4*)(hlo + idx) = lv;
    *(u16x4*)&lds[t][c4] = hv;
  }
  __syncthreads();
#pragma unroll
  for (int it = 0; it < 4; ++it) {
    int e = it * 16 + rr;
    u16x4 wv;
    wv[0] = lds[c4 + 0][e];
    wv[1] = lds[c4 + 1][e];
    wv[2] = lds[c4 + 2][e];
    wv[3] = lds[c4 + 3][e];
    *(u16x4*)(hT + ((size_t)(b * D_DIM + e0 + e)) * T_DIM + t0 + c4) = wv;
  }
}

// ---------------- split+transpose A -> AT_hi/AT_lo ([head][e][d], d contiguous) ----
__global__ __launch_bounds__(256) void split_AT_kernel(const float* __restrict__ A,
    ushort_t* __restrict__ AThi, ushort_t* __restrict__ ATlo) {
  __shared__ ushort_t ldh[64][68];
  __shared__ ushort_t ldl[64][68];
  int x = blockIdx.x;                 // 512 = head(8) x dd(8) x ee(8)
  int hd = x >> 6, dd = (x >> 3) & 7, ee = x & 7;
  int d0 = dd * 64, e0 = ee * 64;
  int rr = threadIdx.x >> 4;
  int c4 = (threadIdx.x & 15) * 4;
#pragma unroll
  for (int it = 0; it < 4; ++it) {
    int d = it * 16 + rr;
    float4 v = *(const float4*)(A + ((size_t)(hd * D_DIM + d0 + d)) * D_DIM + e0 + c4);
    u16x4 hv, lv;
    hv[0] = f2bf(v.x); lv[0] = f2bf(v.x - bf2f(hv[0]));
    hv[1] = f2bf(v.y); lv[1] = f2bf(v.y - bf2f(hv[1]));
    hv[2] = f2bf(v.z); lv[2] = f2bf(v.z - bf2f(hv[2]));
    hv[3] = f2bf(v.w); lv[3] = f2bf(v.w - bf2f(hv[3]));
    *(u16x4*)&ldh[d][c4] = hv;
    *(u16x4*)&ldl[d][c4] = lv;
  }
  __syncthreads();
#pragma unroll
  for (int it = 0; it < 4; ++it) {
    int e = it * 16 + rr;
    u16x4 wh, wl;
    wh[0] = ldh[c4 + 0][e]; wl[0] = ldl[c4 + 0][e];
    wh[1] = ldh[c4 + 1][e]; wl[1] = ldl[c4 + 1][e];
    wh[2] = ldh[c4 + 2][e]; wl[2] = ldl[c4 + 2][e];
    wh[3] = ldh[c4 + 3][e]; wl[3] = ldl[c4 + 3][e];
    size_t o = ((size_t)(hd * D_DIM + e0 + e)) * D_DIM + d0 + c4;
    *(u16x4*)(AThi + o) = wh;
    *(u16x4*)(ATlo + o) = wl;
  }
}

// ---------------- Q-GEMM: Q[b,hd] = h_b @ A_hd  (split precision) -------------------
__global__ __launch_bounds__(256, 2) void qgemm_kernel(
    const ushort_t* __restrict__ hhi, const ushort_t* __restrict__ hlo,
    const ushort_t* __restrict__ AThi, const ushort_t* __restrict__ ATlo,
    ushort_t* __restrict__ Qhi, ushort_t* __restrict__ Qlo) {
  int bid = blockIdx.x;               // 1024 = bh(16) x mt(16) x nt(4)
  int bh = bid >> 6, mt = (bid >> 2) & 15, nt = bid & 3;
  int b = bh >> 3, hd = bh & 7;
  int w = threadIdx.x >> 6, lane = threadIdx.x & 63;
  int g = lane >> 4, c = lane & 15;
  int m0 = mt * 128 + (w >> 1) * 64;
  int n0 = nt * 128 + (w & 1) * 64;
  const ushort_t* ha = hhi + (size_t)b * T_DIM * D_DIM;
  const ushort_t* hb = hlo + (size_t)b * T_DIM * D_DIM;
  const ushort_t* Ba = AThi + (size_t)hd * D_DIM * D_DIM;
  const ushort_t* Bb = ATlo + (size_t)hd * D_DIM * D_DIM;
  f32x4 zero4 = {0.f, 0.f, 0.f, 0.f};
  f32x4 acc[4][4];
#pragma unroll
  for (int i = 0; i < 4; ++i)
#pragma unroll
    for (int j = 0; j < 4; ++j) acc[i][j] = zero4;
  for (int kc = 0; kc < 16; ++kc) {
    int doff = kc * 32 + g * 8;
    bf16x8 ah[4], al[4], bhf[4], blf[4];
#pragma unroll
    for (int mf = 0; mf < 4; ++mf) {
      size_t ro = (size_t)(m0 + 16 * mf + c) * D_DIM + doff;
      ah[mf] = ld8(ha + ro);
      al[mf] = ld8(hb + ro);
    }
#pragma unroll
    for (int nf = 0; nf < 4; ++nf) {
      size_t ro = (size_t)(n0 + 16 * nf + c) * D_DIM + doff;
      bhf[nf] = ld8(Ba + ro);
      blf[nf] = ld8(Bb + ro);
    }
#pragma unroll
    for (int mf = 0; mf < 4; ++mf)
#pragma unroll
      for (int nf = 0; nf < 4; ++nf) {
        acc[mf][nf] = mfma16(ah[mf], bhf[nf], acc[mf][nf]);
        acc[mf][nf] = mfma16(ah[mf], blf[nf], acc[mf][nf]);
        acc[mf][nf] = mfma16(al[mf], bhf[nf], acc[mf][nf]);
      }
  }
  size_t qbase = (size_t)bh * T_DIM * D_DIM;
#pragma unroll
  for (int mf = 0; mf < 4; ++mf)
#pragma unroll
    for (int nf = 0; nf < 4; ++nf)
#pragma unroll
      for (int i2 = 0; i2 < 4; ++i2) {
        int q = m0 + 16 * mf + 4 * g + i2;
        int e = n0 + 16 * nf + c;
        float v = acc[mf][nf][i2];
        ushort_t hi = f2bf(v);
        ushort_t lo = f2bf(v - bf2f(hi));
        Qhi[qbase + (size_t)q * D_DIM + e] = hi;
        Qlo[qbase + (size_t)q * D_DIM + e] = lo;
      }
}

// ---------------- fused causal flash attention ------------------------------------
// grid 512 = qt(32) x bh(16), paired so heavy (high qt) and light tiles balance.
// 4 independent waves per block; wave w owns 16 q-rows; NO __syncthreads (divergent
// causal loop lengths across waves).
__global__ __launch_bounds__(256, 2) void flash_kernel(
    const ushort_t* __restrict__ Qhi, const ushort_t* __restrict__ Qlo,
    const ushort_t* __restrict__ Khi, const ushort_t* __restrict__ Klo,
    const ushort_t* __restrict__ hT, float* __restrict__ out) {
  __shared__ ushort_t plds[4][16][72];
  int i = blockIdx.x;
  int j = (i < 256) ? i : (i - 256);
  int bh = j & 15;
  int qt = (i < 256) ? (31 - (j >> 4)) : (j >> 4);
  int b = bh >> 3;
  int w = threadIdx.x >> 6;
  int lane = threadIdx.x & 63;
  int g = lane >> 4, c = lane & 15;
  int q0w = qt * 64 + w * 16;
  int qg = q0w + c;  // this lane's q-row (column of S^T)
  const ushort_t* qhp = Qhi + ((size_t)bh * T_DIM + qg) * D_DIM;
  const ushort_t* qlp = Qlo + ((size_t)bh * T_DIM + qg) * D_DIM;
  const ushort_t* khb = Khi + (size_t)b * T_DIM * D_DIM;
  const ushort_t* klb = Klo + (size_t)b * T_DIM * D_DIM;
  const ushort_t* vtb = hT + (size_t)b * D_DIM * T_DIM;
  f32x4 zero4 = {0.f, 0.f, 0.f, 0.f};
  f32x4 o[32];
#pragma unroll
  for (int nf = 0; nf < 32; ++nf) o[nf] = zero4;
  float m = -3.0e38f, l = 0.f;
  int ntiles = (q0w + 15) / 64 + 1;
  for (int t = 0; t < ntiles; ++t) {
    int s0 = t * 64;
    f32x4 sacc[4];
#pragma unroll
    for (int mf = 0; mf < 4; ++mf) sacc[mf] = zero4;
    // ---- QK^T (swapped: S^T = K * Q), split precision: hh + hl + lh ----
#pragma unroll
    for (int dk = 0; dk < 16; ++dk) {
      int doff = dk * 32 + g * 8;
      bf16x8 qh = ld8(qhp + doff);
      bf16x8 ql = ld8(qlp + doff);
#pragma unroll
      for (int mf = 0; mf < 4; ++mf) {
        size_t ro = (size_t)(s0 + 16 * mf + c) * D_DIM + doff;
        bf16x8 kh = ld8(khb + ro);
        bf16x8 kl = ld8(klb + ro);
        sacc[mf] = mfma16(kh, qh, sacc[mf]);
        sacc[mf] = mfma16(kh, ql, sacc[mf]);
        sacc[mf] = mfma16(kl, qh, sacc[mf]);
      }
    }
    // ---- causal mask + per-q-row max (q = lane&15; s spans regs + lane groups) ----
    float mt_ = -3.0e38f;
#pragma unroll
    for (int sf = 0; sf < 4; ++sf)
#pragma unroll
      for (int i2 = 0; i2 < 4; ++i2) {
        int sg = s0 + 16 * sf + 4 * g + i2;
        float v = sacc[sf][i2];
        v = (sg <= qg) ? v : -3.0e38f;
        sacc[sf][i2] = v;
        mt_ = fmaxf(mt_, v);
      }
    mt_ = fmaxf(mt_, __shfl_xor(mt_, 16));
    mt_ = fmaxf(mt_, __shfl_xor(mt_, 32));
    float mnew = fmaxf(m, mt_);
    int need = __any(mnew > m);
    float r = __expf(m - mnew);
    float rs = 0.f;
#pragma unroll
    for (int sf = 0; sf < 4; ++sf)
#pragma unroll
      for (int i2 = 0; i2 < 4; ++i2) {
        float p = __expf(sacc[sf][i2] - mnew);
        rs += p;
        plds[w][c][16 * sf + 4 * g + i2] = f2bf(p);
      }
    rs += __shfl_xor(rs, 16);
    rs += __shfl_xor(rs, 32);
    l = l * r + rs;
    m = mnew;
    // ---- rescale O by per-row factor (broadcast from the lane holding that q) ----
    if (need) {
#pragma unroll
      for (int i2 = 0; i2 < 4; ++i2) {
        int src = (lane & 48) | (4 * g + i2);
        float ri = __uint_as_float(
            (unsigned)__builtin_amdgcn_ds_bpermute(src << 2, (int)__float_as_uint(r)));
#pragma unroll
        for (int nf = 0; nf < 32; ++nf) o[nf][i2] *= ri;
      }
    }
    // ---- P relayout via wave-local LDS bounce, then PV ----
    asm volatile("s_waitcnt lgkmcnt(0)" ::: "memory");
    bf16x8 pa0 = *(const bf16x8*)&plds[w][c][g * 8];
    bf16x8 pa1 = *(const bf16x8*)&plds[w][c][32 + g * 8];
#pragma unroll
    for (int nf = 0; nf < 32; ++nf) {
      const ushort_t* vp = vtb + (size_t)(16 * nf + c) * T_DIM + s0 + 8 * g;
      bf16x8 v0 = ld8(vp);
      bf16x8 v1 = ld8(vp + 32);
      o[nf] = mfma16(pa0, v0, o[nf]);
      o[nf] = mfma16(pa1, v1, o[nf]);
    }
  }
  // ---- epilogue: divide by l (broadcast per row) and store ----
#pragma unroll
  for (int i2 = 0; i2 < 4; ++i2) {
    int src = (lane & 48) | (4 * g + i2);
    float li = __uint_as_float(
        (unsigned)__builtin_amdgcn_ds_bpermute(src << 2, (int)__float_as_uint(l)));
    float inv = 1.0f / li;
    int q = q0w + 4 * g + i2;
#pragma unroll
    for (int nf = 0; nf < 32; ++nf) {
      int e = 16 * nf + c;
      out[((size_t)bh * T_DIM + q) * D_DIM + e] = o[nf][i2] * inv;
    }
  }
}

extern "C" void kernel_launch(void* const* d_in, const int* in_sizes, int n_in,
                              void* d_out, int out_size, void* d_ws, size_t ws_size,
                              hipStream_t stream) {
  const float* h = (const float*)d_in[0];
  const float* A = (const float*)d_in[1];
  float* out = (float*)d_out;
  char* ws = (char*)d_ws;
  const size_t SZ_H = (size_t)NB * T_DIM * D_DIM * sizeof(ushort_t);   // 4 MB
  const size_t SZ_A = (size_t)NH * D_DIM * D_DIM * sizeof(ushort_t);   // 4 MB
  const size_t SZ_Q = (size_t)NB * NH * T_DIM * D_DIM * sizeof(ushort_t); // 32 MB
  ushort_t* hhi = (ushort_t*)(ws);
  ushort_t* hlo = (ushort_t*)(ws + SZ_H);
  ushort_t* hT  = (ushort_t*)(ws + 2 * SZ_H);
  ushort_t* AThi = (ushort_t*)(ws + 3 * SZ_H);
  ushort_t* ATlo = (ushort_t*)(ws + 3 * SZ_H + SZ_A);
  ushort_t* Qhi = (ushort_t*)(ws + 3 * SZ_H + 2 * SZ_A);
  ushort_t* Qlo = (ushort_t*)(ws + 3 * SZ_H + 2 * SZ_A + SZ_Q);

  split_h_kernel<<<512, 256, 0, stream>>>(h, hhi, hlo, hT);
  split_AT_kernel<<<512, 256, 0, stream>>>(A, AThi, ATlo);
  qgemm_kernel<<<1024, 256, 0, stream>>>(hhi, hlo, AThi, ATlo, Qhi, Qlo);
  flash_kernel<<<512, 256, 0, stream>>>(Qhi, Qlo, hhi, hlo, hT, out);
}

// Round 5
// 406.885 us; speedup vs baseline: 2.9430x; 2.9430x over previous
//
#include <hip/hip_runtime.h>

typedef unsigned short ushort_t;
typedef __attribute__((ext_vector_type(8))) short bf16x8;
typedef __attribute__((ext_vector_type(4))) float f32x4;
typedef __attribute__((ext_vector_type(4))) unsigned short u16x4;

#define T_DIM 2048
#define D_DIM 512
#define NH 8
#define NB 2
#define PSTRIDE (2 * T_DIM)  // P (bf16) row stride in elements: in-place over S (fp32) rows

static __device__ __forceinline__ ushort_t f2bf(float x) {
  union { float f; unsigned u; } v; v.f = x;
  unsigned r = v.u + 0x7fffu + ((v.u >> 16) & 1u);
  return (ushort_t)(r >> 16);
}
static __device__ __forceinline__ float bf2f(ushort_t b) {
  union { unsigned u; float f; } v; v.u = ((unsigned)b) << 16;
  return v.f;
}
static __device__ __forceinline__ f32x4 mfma16(bf16x8 a, bf16x8 b, f32x4 c) {
  return __builtin_amdgcn_mfma_f32_16x16x32_bf16(a, b, c, 0, 0, 0);
}

typedef const __attribute__((address_space(1))) unsigned asg_t;
typedef __attribute__((address_space(3))) unsigned asl_t;
static __device__ __forceinline__ void gload16(const ushort_t* g, ushort_t* l) {
  __builtin_amdgcn_global_load_lds((asg_t*)g, (asl_t*)l, 16, 0, 0);
}

// stage a [128][32] bf16 tile (8KB) from global rows (stride ldk) into LDS.
// dest: wave-uniform base + lane*16B (HW rule); per-lane global source addresses.
static __device__ __forceinline__ void stage128x32(const ushort_t* __restrict__ src,
                                                   size_t ldk, ushort_t* lds, int tid) {
  int w = tid >> 6;
#pragma unroll
  for (int p = 0; p < 2; ++p) {
    int t = p * 256 + tid;          // 512 chunks of 8 elems
    int r = t >> 2;                 // row 0..127
    int col = (t & 3) << 3;         // 0,8,16,24
    gload16(src + (size_t)r * ldk + col, lds + p * 2048 + (w << 9));
  }
}

// ---------------- split h -> h_hi/h_lo (bf16) + hT (bf16 transpose) ----------------
__global__ __launch_bounds__(256) void split_h_kernel(const float* __restrict__ h,
    ushort_t* __restrict__ hhi, ushort_t* __restrict__ hlo, ushort_t* __restrict__ hT) {
  __shared__ ushort_t lds[64][68];
  int x = blockIdx.x;                 // 512 = b(2) x tt(32) x ee(8)
  int b = x >> 8, tt = (x >> 3) & 31, ee = x & 7;
  int t0 = tt * 64, e0 = ee * 64;
  int rr = threadIdx.x >> 4;
  int c4 = (threadIdx.x & 15) * 4;
#pragma unroll
  for (int it = 0; it < 4; ++it) {
    int t = it * 16 + rr;
    size_t idx = ((size_t)(b * T_DIM + t0 + t)) * D_DIM + e0 + c4;
    float4 v = *(const float4*)(h + idx);
    u16x4 hv, lv;
    hv[0] = f2bf(v.x); lv[0] = f2bf(v.x - bf2f(hv[0]));
    hv[1] = f2bf(v.y); lv[1] = f2bf(v.y - bf2f(hv[1]));
    hv[2] = f2bf(v.z); lv[2] = f2bf(v.z - bf2f(hv[2]));
    hv[3] = f2bf(v.w); lv[3] = f2bf(v.w - bf2f(hv[3]));
    *(u16x4*)(hhi + idx) = hv;
    *(u16x4*)(hlo + idx) = lv;
    *(u16x4*)&lds[t][c4] = hv;
  }
  __syncthreads();
#pragma unroll
  for (int it = 0; it < 4; ++it) {
    int e = it * 16 + rr;
    u16x4 wv;
    wv[0] = lds[c4 + 0][e];
    wv[1] = lds[c4 + 1][e];
    wv[2] = lds[c4 + 2][e];
    wv[3] = lds[c4 + 3][e];
    *(u16x4*)(hT + ((size_t)(b * D_DIM + e0 + e)) * T_DIM + t0 + c4) = wv;
  }
}

// ---------------- split+transpose A -> AT_hi/AT_lo ([head][e][d], d contiguous) ----
__global__ __launch_bounds__(256) void split_AT_kernel(const float* __restrict__ A,
    ushort_t* __restrict__ AThi, ushort_t* __restrict__ ATlo) {
  __shared__ ushort_t ldh[64][68];
  __shared__ ushort_t ldl[64][68];
  int x = blockIdx.x;                 // 512 = head(8) x dd(8) x ee(8)
  int hd = x >> 6, dd = (x >> 3) & 7, ee = x & 7;
  int d0 = dd * 64, e0 = ee * 64;
  int rr = threadIdx.x >> 4;
  int c4 = (threadIdx.x & 15) * 4;
#pragma unroll
  for (int it = 0; it < 4; ++it) {
    int d = it * 16 + rr;
    float4 v = *(const float4*)(A + ((size_t)(hd * D_DIM + d0 + d)) * D_DIM + e0 + c4);
    u16x4 hv, lv;
    hv[0] = f2bf(v.x); lv[0] = f2bf(v.x - bf2f(hv[0]));
    hv[1] = f2bf(v.y); lv[1] = f2bf(v.y - bf2f(hv[1]));
    hv[2] = f2bf(v.z); lv[2] = f2bf(v.z - bf2f(hv[2]));
    hv[3] = f2bf(v.w); lv[3] = f2bf(v.w - bf2f(hv[3]));
    *(u16x4*)&ldh[d][c4] = hv;
    *(u16x4*)&ldl[d][c4] = lv;
  }
  __syncthreads();
#pragma unroll
  for (int it = 0; it < 4; ++it) {
    int e = it * 16 + rr;
    u16x4 wh, wl;
    wh[0] = ldh[c4 + 0][e]; wl[0] = ldl[c4 + 0][e];
    wh[1] = ldh[c4 + 1][e]; wl[1] = ldl[c4 + 1][e];
    wh[2] = ldh[c4 + 2][e]; wl[2] = ldl[c4 + 2][e];
    wh[3] = ldh[c4 + 3][e]; wl[3] = ldl[c4 + 3][e];
    size_t o = ((size_t)(hd * D_DIM + e0 + e)) * D_DIM + d0 + c4;
    *(u16x4*)(AThi + o) = wh;
    *(u16x4*)(ATlo + o) = wl;
  }
}

// ---------------- Q-GEMM: Q[b,hd] = h_b @ A_hd (split x3), m97-style LDS staging ----
__global__ __launch_bounds__(256, 2) void qgemm_kernel(
    const ushort_t* __restrict__ hhi, const ushort_t* __restrict__ hlo,
    const ushort_t* __restrict__ AThi, const ushort_t* __restrict__ ATlo,
    ushort_t* __restrict__ Qhi, ushort_t* __restrict__ Qlo) {
  __shared__ ushort_t lAh[128 * 32], lAl[128 * 32], lBh[128 * 32], lBl[128 * 32];
  int bid = blockIdx.x;               // 1024 = bh(16) x mt(16) x nt(4)
  int bh = bid >> 6, mt = (bid >> 2) & 15, nt = bid & 3;
  int b = bh >> 3, hd = bh & 7;
  int tid = threadIdx.x;
  int w = tid >> 6, lane = tid & 63;
  int g = lane >> 4, c = lane & 15;
  int m0 = (w >> 1) * 64, n0 = (w & 1) * 64;
  const ushort_t* Ah = hhi + (size_t)b * T_DIM * D_DIM + (size_t)(mt * 128) * D_DIM;
  const ushort_t* Al = hlo + (size_t)b * T_DIM * D_DIM + (size_t)(mt * 128) * D_DIM;
  const ushort_t* Bh = AThi + (size_t)hd * D_DIM * D_DIM + (size_t)(nt * 128) * D_DIM;
  const ushort_t* Bl = ATlo + (size_t)hd * D_DIM * D_DIM + (size_t)(nt * 128) * D_DIM;
  f32x4 zero4 = {0.f, 0.f, 0.f, 0.f};
  f32x4 acc[4][4];
#pragma unroll
  for (int i = 0; i < 4; ++i)
#pragma unroll
    for (int j = 0; j < 4; ++j) acc[i][j] = zero4;
  for (int kc = 0; kc < 16; ++kc) {
    int k0 = kc * 32;
    stage128x32(Ah + k0, D_DIM, lAh, tid);
    stage128x32(Al + k0, D_DIM, lAl, tid);
    stage128x32(Bh + k0, D_DIM, lBh, tid);
    stage128x32(Bl + k0, D_DIM, lBl, tid);
    __syncthreads();
    bf16x8 ah[4], al[4], bh8[4], bl8[4];
#pragma unroll
    for (int mf = 0; mf < 4; ++mf) {
      int ro = (m0 + 16 * mf + c) * 32 + g * 8;
      ah[mf] = *(const bf16x8*)&lAh[ro];
      al[mf] = *(const bf16x8*)&lAl[ro];
    }
#pragma unroll
    for (int nf = 0; nf < 4; ++nf) {
      int ro = (n0 + 16 * nf + c) * 32 + g * 8;
      bh8[nf] = *(const bf16x8*)&lBh[ro];
      bl8[nf] = *(const bf16x8*)&lBl[ro];
    }
#pragma unroll
    for (int mf = 0; mf < 4; ++mf)
#pragma unroll
      for (int nf = 0; nf < 4; ++nf) {
        acc[mf][nf] = mfma16(ah[mf], bh8[nf], acc[mf][nf]);
        acc[mf][nf] = mfma16(ah[mf], bl8[nf], acc[mf][nf]);
        acc[mf][nf] = mfma16(al[mf], bh8[nf], acc[mf][nf]);
      }
    __syncthreads();
  }
  size_t qbase = (size_t)bh * T_DIM * D_DIM;
#pragma unroll
  for (int mf = 0; mf < 4; ++mf)
#pragma unroll
    for (int nf = 0; nf < 4; ++nf)
#pragma unroll
      for (int i2 = 0; i2 < 4; ++i2) {
        int q = mt * 128 + m0 + 16 * mf + 4 * g + i2;
        int e = nt * 128 + n0 + 16 * nf + c;
        float v = acc[mf][nf][i2];
        ushort_t hi = f2bf(v);
        ushort_t lo = f2bf(v - bf2f(hi));
        Qhi[qbase + (size_t)q * D_DIM + e] = hi;
        Qlo[qbase + (size_t)q * D_DIM + e] = lo;
      }
}

// ---------------- S-GEMM: causal lower-tri tiles, S = Q @ K^T (split x3) ----------
// S holds heads [hd0, hd0+nhc) at local indices 0..nhc-1.
__global__ __launch_bounds__(256, 2) void sgemm_kernel(
    const ushort_t* __restrict__ Qhi, const ushort_t* __restrict__ Qlo,
    const ushort_t* __restrict__ Khi, const ushort_t* __restrict__ Klo,
    float* __restrict__ S, int b, int hd0) {
  __shared__ ushort_t lAh[128 * 32], lAl[128 * 32], lBh[128 * 32], lBl[128 * 32];
  int i = blockIdx.x;                 // nhc heads x 136 lower-tri tiles
  int ti = i % 136, hdl = i / 136;
  int tq = (int)((sqrtf(8.f * (float)ti + 1.f) - 1.f) * 0.5f);
  while ((tq + 1) * (tq + 2) / 2 <= ti) ++tq;
  while (tq * (tq + 1) / 2 > ti) --tq;
  int ts = ti - tq * (tq + 1) / 2;
  int bh = b * NH + hd0 + hdl;
  int tid = threadIdx.x;
  int w = tid >> 6, lane = tid & 63;
  int g = lane >> 4, c = lane & 15;
  int m0 = (w >> 1) * 64, n0 = (w & 1) * 64;
  const ushort_t* Ah = Qhi + (size_t)bh * T_DIM * D_DIM + (size_t)(tq * 128) * D_DIM;
  const ushort_t* Al = Qlo + (size_t)bh * T_DIM * D_DIM + (size_t)(tq * 128) * D_DIM;
  const ushort_t* Bh = Khi + (size_t)b * T_DIM * D_DIM + (size_t)(ts * 128) * D_DIM;
  const ushort_t* Bl = Klo + (size_t)b * T_DIM * D_DIM + (size_t)(ts * 128) * D_DIM;
  f32x4 zero4 = {0.f, 0.f, 0.f, 0.f};
  f32x4 acc[4][4];
#pragma unroll
  for (int ii = 0; ii < 4; ++ii)
#pragma unroll
    for (int j = 0; j < 4; ++j) acc[ii][j] = zero4;
  for (int kc = 0; kc < 16; ++kc) {
    int k0 = kc * 32;
    stage128x32(Ah + k0, D_DIM, lAh, tid);
    stage128x32(Al + k0, D_DIM, lAl, tid);
    stage128x32(Bh + k0, D_DIM, lBh, tid);
    stage128x32(Bl + k0, D_DIM, lBl, tid);
    __syncthreads();
    bf16x8 ah[4], al[4], bh8[4], bl8[4];
#pragma unroll
    for (int mf = 0; mf < 4; ++mf) {
      int ro = (m0 + 16 * mf + c) * 32 + g * 8;
      ah[mf] = *(const bf16x8*)&lAh[ro];
      al[mf] = *(const bf16x8*)&lAl[ro];
    }
#pragma unroll
    for (int nf = 0; nf < 4; ++nf) {
      int ro = (n0 + 16 * nf + c) * 32 + g * 8;
      bh8[nf] = *(const bf16x8*)&lBh[ro];
      bl8[nf] = *(const bf16x8*)&lBl[ro];
    }
#pragma unroll
    for (int mf = 0; mf < 4; ++mf)
#pragma unroll
      for (int nf = 0; nf < 4; ++nf) {
        acc[mf][nf] = mfma16(ah[mf], bh8[nf], acc[mf][nf]);
        acc[mf][nf] = mfma16(ah[mf], bl8[nf], acc[mf][nf]);
        acc[mf][nf] = mfma16(al[mf], bh8[nf], acc[mf][nf]);
      }
    __syncthreads();
  }
#pragma unroll
  for (int mf = 0; mf < 4; ++mf)
#pragma unroll
    for (int nf = 0; nf < 4; ++nf)
#pragma unroll
      for (int i2 = 0; i2 < 4; ++i2) {
        int q = tq * 128 + m0 + 16 * mf + 4 * g + i2;
        int s = ts * 128 + n0 + 16 * nf + c;
        S[((size_t)(hdl * T_DIM + q)) * T_DIM + s] = acc[mf][nf][i2];
      }
}

// ------- row softmax: S fp32 -> P bf16 IN PLACE (row's first half), zero-padded ----
// Safe aliasing: all fp32-row reads happen before the first __syncthreads; the bf16
// overwrite of the same row happens only after the last one.
__global__ __launch_bounds__(256) void softmax_kernel(float* __restrict__ S) {
  __shared__ float rowbuf[2048];
  __shared__ float red[4];
  int i = blockIdx.x;                 // nhc * 2048
  int hdl = i >> 11, q = i & 2047;
  float* srow = S + ((size_t)(hdl * T_DIM + q)) * T_DIM;
  ushort_t* prow = (ushort_t*)srow;   // in-place, row stride PSTRIDE ushorts
  int n = q + 1;
  int nout = ((q >> 7) + 1) << 7;
  int tid = threadIdx.x;
  float mx = -3.0e38f;
  for (int s0 = tid * 4; s0 < nout; s0 += 1024) {
    float4 v = make_float4(-3.0e38f, -3.0e38f, -3.0e38f, -3.0e38f);
    if (s0 < n) v = *(const float4*)(srow + s0);
    float a0 = (s0 + 0 < n) ? v.x : -3.0e38f;
    float a1 = (s0 + 1 < n) ? v.y : -3.0e38f;
    float a2 = (s0 + 2 < n) ? v.z : -3.0e38f;
    float a3 = (s0 + 3 < n) ? v.w : -3.0e38f;
    rowbuf[s0 + 0] = a0; rowbuf[s0 + 1] = a1;
    rowbuf[s0 + 2] = a2; rowbuf[s0 + 3] = a3;
    mx = fmaxf(mx, fmaxf(fmaxf(a0, a1), fmaxf(a2, a3)));
  }
#pragma unroll
  for (int off = 1; off < 64; off <<= 1) mx = fmaxf(mx, __shfl_xor(mx, off));
  if ((tid & 63) == 0) red[tid >> 6] = mx;
  __syncthreads();
  mx = fmaxf(fmaxf(red[0], red[1]), fmaxf(red[2], red[3]));
  float sum = 0.f;
  for (int s0 = tid * 4; s0 < nout; s0 += 1024) {
    float e0 = __expf(rowbuf[s0 + 0] - mx);
    float e1 = __expf(rowbuf[s0 + 1] - mx);
    float e2 = __expf(rowbuf[s0 + 2] - mx);
    float e3 = __expf(rowbuf[s0 + 3] - mx);
    rowbuf[s0 + 0] = e0; rowbuf[s0 + 1] = e1;
    rowbuf[s0 + 2] = e2; rowbuf[s0 + 3] = e3;
    sum += (e0 + e1) + (e2 + e3);
  }
#pragma unroll
  for (int off = 1; off < 64; off <<= 1) sum += __shfl_xor(sum, off);
  __syncthreads();
  if ((tid & 63) == 0) red[tid >> 6] = sum;
  __syncthreads();
  float inv = 1.0f / ((red[0] + red[1]) + (red[2] + red[3]));
  for (int s0 = tid * 4; s0 < nout; s0 += 1024) {
    u16x4 o;
    o[0] = f2bf(rowbuf[s0 + 0] * inv);
    o[1] = f2bf(rowbuf[s0 + 1] * inv);
    o[2] = f2bf(rowbuf[s0 + 2] * inv);
    o[3] = f2bf(rowbuf[s0 + 3] * inv);
    *(u16x4*)(prow + s0) = o;
  }
}

// ---------------- PV-GEMM: out = P @ h (causal K range), plain bf16 ----------------
__global__ __launch_bounds__(256, 2) void pv_kernel(const ushort_t* __restrict__ P,
    const ushort_t* __restrict__ hT, float* __restrict__ out, int b, int hd0, int nhc) {
  __shared__ ushort_t lA[128 * 32], lB[128 * 32];
  int i = blockIdx.x;                 // nhc*64 = tqi x hdl x nt(4)
  int nt = i & 3;
  int rem = i >> 2;
  int hdl = rem % nhc;
  int tq = 15 - rem / nhc;            // heavy tiles first
  int tid = threadIdx.x;
  int w = tid >> 6, lane = tid & 63;
  int g = lane >> 4, c = lane & 15;
  int m0 = (w >> 1) * 64, n0 = (w & 1) * 64;
  const ushort_t* Ab = P + (size_t)(hdl * T_DIM + tq * 128) * PSTRIDE;
  const ushort_t* Bb = hT + (size_t)b * D_DIM * T_DIM + (size_t)(nt * 128) * T_DIM;
  f32x4 zero4 = {0.f, 0.f, 0.f, 0.f};
  f32x4 acc[4][4];
#pragma unroll
  for (int ii = 0; ii < 4; ++ii)
#pragma unroll
    for (int j = 0; j < 4; ++j) acc[ii][j] = zero4;
  int nk = (tq + 1) * 4;
  for (int kc = 0; kc < nk; ++kc) {
    int k0 = kc * 32;
    stage128x32(Ab + k0, PSTRIDE, lA, tid);
    stage128x32(Bb + k0, T_DIM, lB, tid);
    __syncthreads();
    bf16x8 af[4], bf[4];
#pragma unroll
    for (int mf = 0; mf < 4; ++mf) af[mf] = *(const bf16x8*)&lA[(m0 + 16 * mf + c) * 32 + g * 8];
#pragma unroll
    for (int nf = 0; nf < 4; ++nf) bf[nf] = *(const bf16x8*)&lB[(n0 + 16 * nf + c) * 32 + g * 8];
#pragma unroll
    for (int mf = 0; mf < 4; ++mf)
#pragma unroll
      for (int nf = 0; nf < 4; ++nf) acc[mf][nf] = mfma16(af[mf], bf[nf], acc[mf][nf]);
    __syncthreads();
  }
  size_t obase = (size_t)(b * NH + hd0 + hdl) * T_DIM * D_DIM;
#pragma unroll
  for (int mf = 0; mf < 4; ++mf)
#pragma unroll
    for (int nf = 0; nf < 4; ++nf)
#pragma unroll
      for (int i2 = 0; i2 < 4; ++i2) {
        int q = tq * 128 + m0 + 16 * mf + 4 * g + i2;
        int d = nt * 128 + n0 + 16 * nf + c;
        out[obase + (size_t)q * D_DIM + d] = acc[mf][nf][i2];
      }
}

extern "C" void kernel_launch(void* const* d_in, const int* in_sizes, int n_in,
                              void* d_out, int out_size, void* d_ws, size_t ws_size,
                              hipStream_t stream) {
  const float* h = (const float*)d_in[0];
  const float* A = (const float*)d_in[1];
  float* out = (float*)d_out;
  char* ws = (char*)d_ws;
  const size_t SZ_H = (size_t)NB * T_DIM * D_DIM * sizeof(ushort_t);      // 4 MB
  const size_t SZ_A = (size_t)NH * D_DIM * D_DIM * sizeof(ushort_t);      // 4 MB
  const size_t SZ_Q = (size_t)NB * NH * T_DIM * D_DIM * sizeof(ushort_t); // 33.5 MB
  const size_t SZ_S1 = (size_t)T_DIM * T_DIM * sizeof(float);             // 16.8 MB/head
  const size_t FIXED = 3 * SZ_H + 2 * SZ_A + 2 * SZ_Q;                    // 87.2 MB
  ushort_t* hhi  = (ushort_t*)(ws);
  ushort_t* hlo  = (ushort_t*)(ws + SZ_H);
  ushort_t* hT   = (ushort_t*)(ws + 2 * SZ_H);
  ushort_t* AThi = (ushort_t*)(ws + 3 * SZ_H);
  ushort_t* ATlo = (ushort_t*)(ws + 3 * SZ_H + SZ_A);
  ushort_t* Qhi  = (ushort_t*)(ws + 3 * SZ_H + 2 * SZ_A);
  ushort_t* Qlo  = (ushort_t*)(ws + 3 * SZ_H + 2 * SZ_A + SZ_Q);
  float*    Sbuf = (float*)   (ws + FIXED);

  // largest power-of-two head chunk whose S fits in the remaining workspace
  int nhc = NH;
  while (nhc > 1 && FIXED + (size_t)nhc * SZ_S1 > ws_size) nhc >>= 1;

  split_h_kernel<<<512, 256, 0, stream>>>(h, hhi, hlo, hT);
  split_AT_kernel<<<512, 256, 0, stream>>>(A, AThi, ATlo);
  qgemm_kernel<<<1024, 256, 0, stream>>>(hhi, hlo, AThi, ATlo, Qhi, Qlo);
  for (int b = 0; b < NB; ++b) {
    for (int hc = 0; hc < NH; hc += nhc) {
      sgemm_kernel<<<nhc * 136, 256, 0, stream>>>(Qhi, Qlo, hhi, hlo, Sbuf, b, hc);
      softmax_kernel<<<nhc * T_DIM, 256, 0, stream>>>(Sbuf);
      pv_kernel<<<nhc * 64, 256, 0, stream>>>((const ushort_t*)Sbuf, hT, out, b, hc, nhc);
    }
  }
}

// Round 6
// 399.442 us; speedup vs baseline: 2.9979x; 1.0186x over previous
//
#include <hip/hip_runtime.h>

typedef unsigned short ushort_t;
typedef __attribute__((ext_vector_type(8))) short bf16x8;
typedef __attribute__((ext_vector_type(4))) float f32x4;
typedef __attribute__((ext_vector_type(4))) unsigned short u16x4;

#define T_DIM 2048
#define D_DIM 512
#define NH 8
#define NB 2
#define PSTRIDE (2 * T_DIM)  // P (bf16) row stride in elements: in-place over S (fp32) rows

static __device__ __forceinline__ ushort_t f2bf(float x) {
  union { float f; unsigned u; } v; v.f = x;
  unsigned r = v.u + 0x7fffu + ((v.u >> 16) & 1u);
  return (ushort_t)(r >> 16);
}
static __device__ __forceinline__ float bf2f(ushort_t b) {
  union { unsigned u; float f; } v; v.u = ((unsigned)b) << 16;
  return v.f;
}
static __device__ __forceinline__ f32x4 mfma16(bf16x8 a, bf16x8 b, f32x4 c) {
  return __builtin_amdgcn_mfma_f32_16x16x32_bf16(a, b, c, 0, 0, 0);
}

typedef const __attribute__((address_space(1))) unsigned asg_t;
typedef __attribute__((address_space(3))) unsigned asl_t;
static __device__ __forceinline__ void gload16(const ushort_t* g, ushort_t* l) {
  __builtin_amdgcn_global_load_lds((asg_t*)g, (asl_t*)l, 16, 0, 0);
}

// stage a [128][32] bf16 tile (8KB) from global rows (stride ldk) into LDS.
// dest: wave-uniform base + lane*16B (HW rule); per-lane global source addresses.
static __device__ __forceinline__ void stage128x32(const ushort_t* __restrict__ src,
                                                   size_t ldk, ushort_t* lds, int tid) {
  int w = tid >> 6;
#pragma unroll
  for (int p = 0; p < 2; ++p) {
    int t = p * 256 + tid;          // 512 chunks of 8 elems
    int r = t >> 2;                 // row 0..127
    int col = (t & 3) << 3;         // 0,8,16,24
    gload16(src + (size_t)r * ldk + col, lds + p * 2048 + (w << 9));
  }
}

// ---------------- split h -> h_hi/h_lo (bf16) + hT (bf16 transpose) ----------------
__global__ __launch_bounds__(256) void split_h_kernel(const float* __restrict__ h,
    ushort_t* __restrict__ hhi, ushort_t* __restrict__ hlo, ushort_t* __restrict__ hT) {
  __shared__ ushort_t lds[64][68];
  int x = blockIdx.x;                 // 512 = b(2) x tt(32) x ee(8)
  int b = x >> 8, tt = (x >> 3) & 31, ee = x & 7;
  int t0 = tt * 64, e0 = ee * 64;
  int rr = threadIdx.x >> 4;
  int c4 = (threadIdx.x & 15) * 4;
#pragma unroll
  for (int it = 0; it < 4; ++it) {
    int t = it * 16 + rr;
    size_t idx = ((size_t)(b * T_DIM + t0 + t)) * D_DIM + e0 + c4;
    float4 v = *(const float4*)(h + idx);
    u16x4 hv, lv;
    hv[0] = f2bf(v.x); lv[0] = f2bf(v.x - bf2f(hv[0]));
    hv[1] = f2bf(v.y); lv[1] = f2bf(v.y - bf2f(hv[1]));
    hv[2] = f2bf(v.z); lv[2] = f2bf(v.z - bf2f(hv[2]));
    hv[3] = f2bf(v.w); lv[3] = f2bf(v.w - bf2f(hv[3]));
    *(u16x4*)(hhi + idx) = hv;
    *(u16x4*)(hlo + idx) = lv;
    *(u16x4*)&lds[t][c4] = hv;
  }
  __syncthreads();
#pragma unroll
  for (int it = 0; it < 4; ++it) {
    int e = it * 16 + rr;
    u16x4 wv;
    wv[0] = lds[c4 + 0][e];
    wv[1] = lds[c4 + 1][e];
    wv[2] = lds[c4 + 2][e];
    wv[3] = lds[c4 + 3][e];
    *(u16x4*)(hT + ((size_t)(b * D_DIM + e0 + e)) * T_DIM + t0 + c4) = wv;
  }
}

// ---------------- split+transpose A -> AT_hi/AT_lo ([head][e][d], d contiguous) ----
__global__ __launch_bounds__(256) void split_AT_kernel(const float* __restrict__ A,
    ushort_t* __restrict__ AThi, ushort_t* __restrict__ ATlo) {
  __shared__ ushort_t ldh[64][68];
  __shared__ ushort_t ldl[64][68];
  int x = blockIdx.x;                 // 512 = head(8) x dd(8) x ee(8)
  int hd = x >> 6, dd = (x >> 3) & 7, ee = x & 7;
  int d0 = dd * 64, e0 = ee * 64;
  int rr = threadIdx.x >> 4;
  int c4 = (threadIdx.x & 15) * 4;
#pragma unroll
  for (int it = 0; it < 4; ++it) {
    int d = it * 16 + rr;
    float4 v = *(const float4*)(A + ((size_t)(hd * D_DIM + d0 + d)) * D_DIM + e0 + c4);
    u16x4 hv, lv;
    hv[0] = f2bf(v.x); lv[0] = f2bf(v.x - bf2f(hv[0]));
    hv[1] = f2bf(v.y); lv[1] = f2bf(v.y - bf2f(hv[1]));
    hv[2] = f2bf(v.z); lv[2] = f2bf(v.z - bf2f(hv[2]));
    hv[3] = f2bf(v.w); lv[3] = f2bf(v.w - bf2f(hv[3]));
    *(u16x4*)&ldh[d][c4] = hv;
    *(u16x4*)&ldl[d][c4] = lv;
  }
  __syncthreads();
#pragma unroll
  for (int it = 0; it < 4; ++it) {
    int e = it * 16 + rr;
    u16x4 wh, wl;
    wh[0] = ldh[c4 + 0][e]; wl[0] = ldl[c4 + 0][e];
    wh[1] = ldh[c4 + 1][e]; wl[1] = ldl[c4 + 1][e];
    wh[2] = ldh[c4 + 2][e]; wl[2] = ldl[c4 + 2][e];
    wh[3] = ldh[c4 + 3][e]; wl[3] = ldl[c4 + 3][e];
    size_t o = ((size_t)(hd * D_DIM + e0 + e)) * D_DIM + d0 + c4;
    *(u16x4*)(AThi + o) = wh;
    *(u16x4*)(ATlo + o) = wl;
  }
}

// ---------------- Q-GEMM: Q[b,hd] = h_b @ A_hd (split x3), m97-style LDS staging ----
// blockIdx decode: hd fastest (bid & 7) -> head<->XCD affinity (dispatch round-robins
// blockIdx across the 8 XCDs); per-XCD working set = h_b (4MB) + AT head (1MB).
__global__ __launch_bounds__(256, 2) void qgemm_kernel(
    const ushort_t* __restrict__ hhi, const ushort_t* __restrict__ hlo,
    const ushort_t* __restrict__ AThi, const ushort_t* __restrict__ ATlo,
    ushort_t* __restrict__ Qhi, ushort_t* __restrict__ Qlo) {
  __shared__ ushort_t lAh[128 * 32], lAl[128 * 32], lBh[128 * 32], lBl[128 * 32];
  int bid = blockIdx.x;               // 1024 = mt(16) x nt(4) x b(2) x hd(8), hd fastest
  int hd = bid & 7;
  int rem = bid >> 3;                 // 0..127
  int nt = rem & 3;
  int mt = (rem >> 2) & 15;
  int b = rem >> 6;
  int bh = b * NH + hd;
  int tid = threadIdx.x;
  int w = tid >> 6, lane = tid & 63;
  int g = lane >> 4, c = lane & 15;
  int m0 = (w >> 1) * 64, n0 = (w & 1) * 64;
  const ushort_t* Ah = hhi + (size_t)b * T_DIM * D_DIM + (size_t)(mt * 128) * D_DIM;
  const ushort_t* Al = hlo + (size_t)b * T_DIM * D_DIM + (size_t)(mt * 128) * D_DIM;
  const ushort_t* Bh = AThi + (size_t)hd * D_DIM * D_DIM + (size_t)(nt * 128) * D_DIM;
  const ushort_t* Bl = ATlo + (size_t)hd * D_DIM * D_DIM + (size_t)(nt * 128) * D_DIM;
  f32x4 zero4 = {0.f, 0.f, 0.f, 0.f};
  f32x4 acc[4][4];
#pragma unroll
  for (int i = 0; i < 4; ++i)
#pragma unroll
    for (int j = 0; j < 4; ++j) acc[i][j] = zero4;
  for (int kc = 0; kc < 16; ++kc) {
    int k0 = kc * 32;
    stage128x32(Ah + k0, D_DIM, lAh, tid);
    stage128x32(Al + k0, D_DIM, lAl, tid);
    stage128x32(Bh + k0, D_DIM, lBh, tid);
    stage128x32(Bl + k0, D_DIM, lBl, tid);
    __syncthreads();
    bf16x8 ah[4], al[4], bh8[4], bl8[4];
#pragma unroll
    for (int mf = 0; mf < 4; ++mf) {
      int ro = (m0 + 16 * mf + c) * 32 + g * 8;
      ah[mf] = *(const bf16x8*)&lAh[ro];
      al[mf] = *(const bf16x8*)&lAl[ro];
    }
#pragma unroll
    for (int nf = 0; nf < 4; ++nf) {
      int ro = (n0 + 16 * nf + c) * 32 + g * 8;
      bh8[nf] = *(const bf16x8*)&lBh[ro];
      bl8[nf] = *(const bf16x8*)&lBl[ro];
    }
#pragma unroll
    for (int mf = 0; mf < 4; ++mf)
#pragma unroll
      for (int nf = 0; nf < 4; ++nf) {
        acc[mf][nf] = mfma16(ah[mf], bh8[nf], acc[mf][nf]);
        acc[mf][nf] = mfma16(ah[mf], bl8[nf], acc[mf][nf]);
        acc[mf][nf] = mfma16(al[mf], bh8[nf], acc[mf][nf]);
      }
    __syncthreads();
  }
  size_t qbase = (size_t)bh * T_DIM * D_DIM;
#pragma unroll
  for (int mf = 0; mf < 4; ++mf)
#pragma unroll
    for (int nf = 0; nf < 4; ++nf)
#pragma unroll
      for (int i2 = 0; i2 < 4; ++i2) {
        int q = mt * 128 + m0 + 16 * mf + 4 * g + i2;
        int e = nt * 128 + n0 + 16 * nf + c;
        float v = acc[mf][nf][i2];
        ushort_t hi = f2bf(v);
        ushort_t lo = f2bf(v - bf2f(hi));
        Qhi[qbase + (size_t)q * D_DIM + e] = hi;
        Qlo[qbase + (size_t)q * D_DIM + e] = lo;
      }
}

// ---------------- S-GEMM: causal lower-tri tiles, S = Q @ K^T (split x3) ----------
// S holds heads [hd0, hd0+nhc) at local indices 0..nhc-1.
// blockIdx decode: head fastest (i % nhc) -> with nhc=8 each head pins to one XCD,
// whose L2 then holds that head's Q panel (4MB) + the shared K panel (4MB).
__global__ __launch_bounds__(256, 2) void sgemm_kernel(
    const ushort_t* __restrict__ Qhi, const ushort_t* __restrict__ Qlo,
    const ushort_t* __restrict__ Khi, const ushort_t* __restrict__ Klo,
    float* __restrict__ S, int b, int hd0) {
  __shared__ ushort_t lAh[128 * 32], lAl[128 * 32], lBh[128 * 32], lBl[128 * 32];
  int nhc = gridDim.x / 136;
  int i = blockIdx.x;                 // nhc heads (fastest) x 136 lower-tri tiles
  int hdl = i % nhc, ti = i / nhc;
  int tq = (int)((sqrtf(8.f * (float)ti + 1.f) - 1.f) * 0.5f);
  while ((tq + 1) * (tq + 2) / 2 <= ti) ++tq;
  while (tq * (tq + 1) / 2 > ti) --tq;
  int ts = ti - tq * (tq + 1) / 2;
  int bh = b * NH + hd0 + hdl;
  int tid = threadIdx.x;
  int w = tid >> 6, lane = tid & 63;
  int g = lane >> 4, c = lane & 15;
  int m0 = (w >> 1) * 64, n0 = (w & 1) * 64;
  const ushort_t* Ah = Qhi + (size_t)bh * T_DIM * D_DIM + (size_t)(tq * 128) * D_DIM;
  const ushort_t* Al = Qlo + (size_t)bh * T_DIM * D_DIM + (size_t)(tq * 128) * D_DIM;
  const ushort_t* Bh = Khi + (size_t)b * T_DIM * D_DIM + (size_t)(ts * 128) * D_DIM;
  const ushort_t* Bl = Klo + (size_t)b * T_DIM * D_DIM + (size_t)(ts * 128) * D_DIM;
  f32x4 zero4 = {0.f, 0.f, 0.f, 0.f};
  f32x4 acc[4][4];
#pragma unroll
  for (int ii = 0; ii < 4; ++ii)
#pragma unroll
    for (int j = 0; j < 4; ++j) acc[ii][j] = zero4;
  for (int kc = 0; kc < 16; ++kc) {
    int k0 = kc * 32;
    stage128x32(Ah + k0, D_DIM, lAh, tid);
    stage128x32(Al + k0, D_DIM, lAl, tid);
    stage128x32(Bh + k0, D_DIM, lBh, tid);
    stage128x32(Bl + k0, D_DIM, lBl, tid);
    __syncthreads();
    bf16x8 ah[4], al[4], bh8[4], bl8[4];
#pragma unroll
    for (int mf = 0; mf < 4; ++mf) {
      int ro = (m0 + 16 * mf + c) * 32 + g * 8;
      ah[mf] = *(const bf16x8*)&lAh[ro];
      al[mf] = *(const bf16x8*)&lAl[ro];
    }
#pragma unroll
    for (int nf = 0; nf < 4; ++nf) {
      int ro = (n0 + 16 * nf + c) * 32 + g * 8;
      bh8[nf] = *(const bf16x8*)&lBh[ro];
      bl8[nf] = *(const bf16x8*)&lBl[ro];
    }
#pragma unroll
    for (int mf = 0; mf < 4; ++mf)
#pragma unroll
      for (int nf = 0; nf < 4; ++nf) {
        acc[mf][nf] = mfma16(ah[mf], bh8[nf], acc[mf][nf]);
        acc[mf][nf] = mfma16(ah[mf], bl8[nf], acc[mf][nf]);
        acc[mf][nf] = mfma16(al[mf], bh8[nf], acc[mf][nf]);
      }
    __syncthreads();
  }
#pragma unroll
  for (int mf = 0; mf < 4; ++mf)
#pragma unroll
    for (int nf = 0; nf < 4; ++nf)
#pragma unroll
      for (int i2 = 0; i2 < 4; ++i2) {
        int q = tq * 128 + m0 + 16 * mf + 4 * g + i2;
        int s = ts * 128 + n0 + 16 * nf + c;
        S[((size_t)(hdl * T_DIM + q)) * T_DIM + s] = acc[mf][nf][i2];
      }
}

// ------- row softmax: S fp32 -> P bf16 IN PLACE (row's first half), zero-padded ----
// Safe aliasing: all fp32-row reads happen before the first __syncthreads; the bf16
// overwrite of the same row happens only after the last one.
__global__ __launch_bounds__(256) void softmax_kernel(float* __restrict__ S) {
  __shared__ float rowbuf[2048];
  __shared__ float red[4];
  int nhc = gridDim.x >> 11;          // grid = nhc * 2048
  int i = blockIdx.x;                 // head fastest -> head<->XCD affinity
  int hdl = i % nhc, q = i / nhc;
  float* srow = S + ((size_t)(hdl * T_DIM + q)) * T_DIM;
  ushort_t* prow = (ushort_t*)srow;   // in-place, row stride PSTRIDE ushorts
  int n = q + 1;
  int nout = ((q >> 7) + 1) << 7;
  int tid = threadIdx.x;
  float mx = -3.0e38f;
  for (int s0 = tid * 4; s0 < nout; s0 += 1024) {
    float4 v = make_float4(-3.0e38f, -3.0e38f, -3.0e38f, -3.0e38f);
    if (s0 < n) v = *(const float4*)(srow + s0);
    float a0 = (s0 + 0 < n) ? v.x : -3.0e38f;
    float a1 = (s0 + 1 < n) ? v.y : -3.0e38f;
    float a2 = (s0 + 2 < n) ? v.z : -3.0e38f;
    float a3 = (s0 + 3 < n) ? v.w : -3.0e38f;
    rowbuf[s0 + 0] = a0; rowbuf[s0 + 1] = a1;
    rowbuf[s0 + 2] = a2; rowbuf[s0 + 3] = a3;
    mx = fmaxf(mx, fmaxf(fmaxf(a0, a1), fmaxf(a2, a3)));
  }
#pragma unroll
  for (int off = 1; off < 64; off <<= 1) mx = fmaxf(mx, __shfl_xor(mx, off));
  if ((tid & 63) == 0) red[tid >> 6] = mx;
  __syncthreads();
  mx = fmaxf(fmaxf(red[0], red[1]), fmaxf(red[2], red[3]));
  float sum = 0.f;
  for (int s0 = tid * 4; s0 < nout; s0 += 1024) {
    float e0 = __expf(rowbuf[s0 + 0] - mx);
    float e1 = __expf(rowbuf[s0 + 1] - mx);
    float e2 = __expf(rowbuf[s0 + 2] - mx);
    float e3 = __expf(rowbuf[s0 + 3] - mx);
    rowbuf[s0 + 0] = e0; rowbuf[s0 + 1] = e1;
    rowbuf[s0 + 2] = e2; rowbuf[s0 + 3] = e3;
    sum += (e0 + e1) + (e2 + e3);
  }
#pragma unroll
  for (int off = 1; off < 64; off <<= 1) sum += __shfl_xor(sum, off);
  __syncthreads();
  if ((tid & 63) == 0) red[tid >> 6] = sum;
  __syncthreads();
  float inv = 1.0f / ((red[0] + red[1]) + (red[2] + red[3]));
  for (int s0 = tid * 4; s0 < nout; s0 += 1024) {
    u16x4 o;
    o[0] = f2bf(rowbuf[s0 + 0] * inv);
    o[1] = f2bf(rowbuf[s0 + 1] * inv);
    o[2] = f2bf(rowbuf[s0 + 2] * inv);
    o[3] = f2bf(rowbuf[s0 + 3] * inv);
    *(u16x4*)(prow + s0) = o;
  }
}

// ---------------- PV-GEMM: out = P @ h (causal K range), plain bf16 ----------------
// blockIdx decode: head fastest -> head<->XCD affinity; heavy tq first within head.
__global__ __launch_bounds__(256, 2) void pv_kernel(const ushort_t* __restrict__ P,
    const ushort_t* __restrict__ hT, float* __restrict__ out, int b, int hd0, int nhc) {
  __shared__ ushort_t lA[128 * 32], lB[128 * 32];
  int i = blockIdx.x;                 // nhc*64 = hdl (fastest) x tqi x nt(4)
  int hdl = i % nhc;
  int rem = i / nhc;
  int nt = rem & 3;
  int tq = 15 - (rem >> 2);           // heavy tiles first
  int tid = threadIdx.x;
  int w = tid >> 6, lane = tid & 63;
  int g = lane >> 4, c = lane & 15;
  int m0 = (w >> 1) * 64, n0 = (w & 1) * 64;
  const ushort_t* Ab = P + (size_t)(hdl * T_DIM + tq * 128) * PSTRIDE;
  const ushort_t* Bb = hT + (size_t)b * D_DIM * T_DIM + (size_t)(nt * 128) * T_DIM;
  f32x4 zero4 = {0.f, 0.f, 0.f, 0.f};
  f32x4 acc[4][4];
#pragma unroll
  for (int ii = 0; ii < 4; ++ii)
#pragma unroll
    for (int j = 0; j < 4; ++j) acc[ii][j] = zero4;
  int nk = (tq + 1) * 4;
  for (int kc = 0; kc < nk; ++kc) {
    int k0 = kc * 32;
    stage128x32(Ab + k0, PSTRIDE, lA, tid);
    stage128x32(Bb + k0, T_DIM, lB, tid);
    __syncthreads();
    bf16x8 af[4], bf[4];
#pragma unroll
    for (int mf = 0; mf < 4; ++mf) af[mf] = *(const bf16x8*)&lA[(m0 + 16 * mf + c) * 32 + g * 8];
#pragma unroll
    for (int nf = 0; nf < 4; ++nf) bf[nf] = *(const bf16x8*)&lB[(n0 + 16 * nf + c) * 32 + g * 8];
#pragma unroll
    for (int mf = 0; mf < 4; ++mf)
#pragma unroll
      for (int nf = 0; nf < 4; ++nf) acc[mf][nf] = mfma16(af[mf], bf[nf], acc[mf][nf]);
    __syncthreads();
  }
  size_t obase = (size_t)(b * NH + hd0 + hdl) * T_DIM * D_DIM;
#pragma unroll
  for (int mf = 0; mf < 4; ++mf)
#pragma unroll
    for (int nf = 0; nf < 4; ++nf)
#pragma unroll
      for (int i2 = 0; i2 < 4; ++i2) {
        int q = tq * 128 + m0 + 16 * mf + 4 * g + i2;
        int d = nt * 128 + n0 + 16 * nf + c;
        out[obase + (size_t)q * D_DIM + d] = acc[mf][nf][i2];
      }
}

extern "C" void kernel_launch(void* const* d_in, const int* in_sizes, int n_in,
                              void* d_out, int out_size, void* d_ws, size_t ws_size,
                              hipStream_t stream) {
  const float* h = (const float*)d_in[0];
  const float* A = (const float*)d_in[1];
  float* out = (float*)d_out;
  char* ws = (char*)d_ws;
  const size_t SZ_H = (size_t)NB * T_DIM * D_DIM * sizeof(ushort_t);      // 4 MB
  const size_t SZ_A = (size_t)NH * D_DIM * D_DIM * sizeof(ushort_t);      // 4 MB
  const size_t SZ_Q = (size_t)NB * NH * T_DIM * D_DIM * sizeof(ushort_t); // 33.5 MB
  const size_t SZ_S1 = (size_t)T_DIM * T_DIM * sizeof(float);             // 16.8 MB/head
  const size_t FIXED = 3 * SZ_H + 2 * SZ_A + 2 * SZ_Q;                    // 87.2 MB
  ushort_t* hhi  = (ushort_t*)(ws);
  ushort_t* hlo  = (ushort_t*)(ws + SZ_H);
  ushort_t* hT   = (ushort_t*)(ws + 2 * SZ_H);
  ushort_t* AThi = (ushort_t*)(ws + 3 * SZ_H);
  ushort_t* ATlo = (ushort_t*)(ws + 3 * SZ_H + SZ_A);
  ushort_t* Qhi  = (ushort_t*)(ws + 3 * SZ_H + 2 * SZ_A);
  ushort_t* Qlo  = (ushort_t*)(ws + 3 * SZ_H + 2 * SZ_A + SZ_Q);
  float*    Sbuf = (float*)   (ws + FIXED);

  // largest power-of-two head chunk whose S fits in the remaining workspace
  int nhc = NH;
  while (nhc > 1 && FIXED + (size_t)nhc * SZ_S1 > ws_size) nhc >>= 1;

  split_h_kernel<<<512, 256, 0, stream>>>(h, hhi, hlo, hT);
  split_AT_kernel<<<512, 256, 0, stream>>>(A, AThi, ATlo);
  qgemm_kernel<<<1024, 256, 0, stream>>>(hhi, hlo, AThi, ATlo, Qhi, Qlo);
  for (int b = 0; b < NB; ++b) {
    for (int hc = 0; hc < NH; hc += nhc) {
      sgemm_kernel<<<nhc * 136, 256, 0, stream>>>(Qhi, Qlo, hhi, hlo, Sbuf, b, hc);
      softmax_kernel<<<nhc * T_DIM, 256, 0, stream>>>(Sbuf);
      pv_kernel<<<nhc * 64, 256, 0, stream>>>((const ushort_t*)Sbuf, hT, out, b, hc, nhc);
    }
  }
}